// Round 1
// baseline (67.263 us; speedup 1.0000x reference)
//
#include <hip/hip_runtime.h>

#define LAMB_COORD 5.0f
#define LAMB_NOOBJ 0.5f
#define GEPS 1e-7f

// gt/pred: (B=16384, C=30, H=7, W=7) fp32 contiguous. 49 cells per (b), 30 channels,
// channel stride = 49 floats. One thread per cell.

__device__ __forceinline__ float giou_loss(const float b1x1, const float b1y1,
                                           const float b1x2, const float b1y2,
                                           const float b2x1, const float b2y1,
                                           const float b2x2, const float b2y2) {
    float ix1 = fmaxf(b1x1, b2x1);
    float iy1 = fmaxf(b1y1, b2y1);
    float ix2 = fminf(b1x2, b2x2);
    float iy2 = fminf(b1y2, b2y2);
    float inter = fmaxf(ix2 - ix1, 0.0f) * fmaxf(iy2 - iy1, 0.0f);
    float a1 = (b1x2 - b1x1) * (b1y2 - b1y1);
    float a2 = (b2x2 - b2x1) * (b2y2 - b2y1);
    float uni = a1 + a2 - inter;
    float iou = inter / (uni + GEPS);
    float cx1 = fminf(b1x1, b2x1);
    float cy1 = fminf(b1y1, b2y1);
    float cx2 = fmaxf(b1x2, b2x2);
    float cy2 = fmaxf(b1y2, b2y2);
    float enc = (cx2 - cx1) * (cy2 - cy1);
    float giou = iou - (enc - uni) / (enc + GEPS);
    return 1.0f - giou;
}

__global__ __launch_bounds__(256) void yolo_loss_kernel(
        const float* __restrict__ gt, const float* __restrict__ pred,
        float* __restrict__ out, int ncells) {
    const int stride = gridDim.x * blockDim.x;
    float local = 0.0f;

    for (int i = blockIdx.x * blockDim.x + threadIdx.x; i < ncells; i += stride) {
        const int b  = i / 49;
        const int hw = i - b * 49;
        const float* __restrict__ g = gt   + (size_t)b * 1470 + hw;
        const float* __restrict__ p = pred + (size_t)b * 1470 + hw;

        // Load channels 0..9 of gt and pred (coalesced per channel across lanes)
        float gch[10], pch[10];
        #pragma unroll
        for (int c = 0; c < 10; ++c) {
            gch[c] = g[c * 49];
            pch[c] = p[c * 49];
        }

        // Boxes in xyxy: gt box from gt ch 0..3; pred boxes from pred ch 0..3 and 5..8
        float l1 = giou_loss(gch[0], gch[1], gch[0] + gch[2], gch[1] + gch[3],
                             pch[0], pch[1], pch[0] + pch[2], pch[1] + pch[3]);
        float l2 = giou_loss(gch[0], gch[1], gch[0] + gch[2], gch[1] + gch[3],
                             pch[5], pch[6], pch[5] + pch[7], pch[6] + pch[8]);

        // argmax over [l1, l2], first-max tie-break (jnp.argmax): arg=1 iff l2 > l1
        float r0, r1;
        if (l2 > l1) { r0 = 0.0f;    r1 = gch[9]; }
        else         { r0 = gch[4];  r1 = 0.0f;   }
        const float appears = fmaxf(r0, r1);

        float s = 0.0f;
        float d;
        // xy SSE: gt/pred channels {0,1} masked r0, {5,6} masked r1, * 5
        d = gch[0] - pch[0]; s += d * d * r0 * LAMB_COORD;
        d = gch[1] - pch[1]; s += d * d * r0 * LAMB_COORD;
        d = gch[5] - pch[5]; s += d * d * r1 * LAMB_COORD;
        d = gch[6] - pch[6]; s += d * d * r1 * LAMB_COORD;
        // wh SSE on sqrt: channels {2,3} r0, {7,8} r1, * 5
        d = sqrtf(gch[2]) - sqrtf(pch[2]); s += d * d * r0 * LAMB_COORD;
        d = sqrtf(gch[3]) - sqrtf(pch[3]); s += d * d * r0 * LAMB_COORD;
        d = sqrtf(gch[7]) - sqrtf(pch[7]); s += d * d * r1 * LAMB_COORD;
        d = sqrtf(gch[8]) - sqrtf(pch[8]); s += d * d * r1 * LAMB_COORD;
        // confidence: channels 4 (r0), 9 (r1): d2*r + d2*(1-r)*0.5
        d = gch[4] - pch[4]; { float d2 = d * d; s += d2 * r0 + d2 * (1.0f - r0) * LAMB_NOOBJ; }
        d = gch[9] - pch[9]; { float d2 = d * d; s += d2 * r1 + d2 * (1.0f - r1) * LAMB_NOOBJ; }
        // class SSE: channels 10..29, masked by appears
        float cls = 0.0f;
        #pragma unroll
        for (int c = 10; c < 30; ++c) {
            float dc = g[c * 49] - p[c * 49];
            cls += dc * dc;
        }
        s += cls * appears;

        local += s;
    }

    // 64-lane wave reduction
    #pragma unroll
    for (int off = 32; off > 0; off >>= 1)
        local += __shfl_down(local, off, 64);

    __shared__ float wsum[4];  // 256 threads = 4 waves
    const int lane = threadIdx.x & 63;
    const int wid  = threadIdx.x >> 6;
    if (lane == 0) wsum[wid] = local;
    __syncthreads();
    if (threadIdx.x == 0) {
        float bsum = wsum[0] + wsum[1] + wsum[2] + wsum[3];
        atomicAdd(out, bsum);
    }
}

extern "C" void kernel_launch(void* const* d_in, const int* in_sizes, int n_in,
                              void* d_out, int out_size, void* d_ws, size_t ws_size,
                              hipStream_t stream) {
    const float* gt   = (const float*)d_in[0];
    const float* pred = (const float*)d_in[1];
    float* out = (float*)d_out;

    const int B = in_sizes[0] / (30 * 49);  // 16384
    const int ncells = B * 49;              // 802816

    // d_out is poisoned before timing and not restored between replays.
    hipMemsetAsync(out, 0, sizeof(float) * out_size, stream);

    const int block = 256;
    const int grid = (ncells + block - 1) / block;  // 3136 blocks
    yolo_loss_kernel<<<grid, block, 0, stream>>>(gt, pred, out, ncells);
}